// Round 5
// baseline (1080.449 us; speedup 1.0000x reference)
//
#include <hip/hip_runtime.h>
#include <hip/hip_bf16.h>
#include <stdint.h>
#include <stddef.h>

// GRU policy: B=2048, T=100, H=256, IN=48 (32 state + 16 ref), ACT=2.
// R5 (= R4 resubmit; R4 bench died with an infra ExceptionGroup, no data):
//     M=8 rows/WG, grid=256 (all CUs busy; MFMA rows 8..15 are finite
//     duplicates, quarantined), xg1c re-blocked to 8-row blocks with depth-1
//     register prefetch in k_layer1, k_xg1 at grid Tc*16, gates n+z*(h-n).
//     Weights stay asm-forced resident (R3: WRITE_SIZE shows no spills).

#define OBS_STRIDE 1632
#define H 256
#define M 8
#define THREADS 512

typedef __attribute__((ext_vector_type(8))) short bfrag8;   // 8 bf16 (4 VGPR)
typedef __attribute__((ext_vector_type(4))) short bfrag4;   // 4 bf16 (8B)
typedef __attribute__((ext_vector_type(4))) float floatx4;  // MFMA C/D

#define MFMA16(a, b, c) __builtin_amdgcn_mfma_f32_16x16x32_bf16((a), (b), (c), 0, 0, 0)

__device__ __forceinline__ unsigned short f2bf(float f) {
  union { float f; unsigned int i; } v; v.f = f;
  unsigned int i = v.i + 0x7FFFu + ((v.i >> 16) & 1u);  // RNE
  return (unsigned short)(i >> 16);
}
__device__ __forceinline__ float bf2f(unsigned short u) {
  union { unsigned int i; float f; } v; v.i = ((unsigned int)u) << 16; return v.f;
}
__device__ __forceinline__ float fast_sigmoid(float x) {
  return 1.f / (1.f + __expf(-x));
}
__device__ __forceinline__ float fast_tanh(float x) {
  x = fminf(fmaxf(x, -15.f), 15.f);
  float e = __expf(2.f * x);
  return (e - 1.f) / (e + 1.f);
}

// Forced (non-rematerializable) 16B global load -> stays in VGPR/AGPR file.
__device__ __forceinline__ void ld16_async(bfrag8& d, const unsigned short* p) {
  asm volatile("global_load_dwordx4 %0, %1, off" : "=v"(d) : "v"(p));
}
__device__ __forceinline__ void wait6(bfrag8& a, bfrag8& b, bfrag8& c,
                                      bfrag8& d, bfrag8& e, bfrag8& f) {
  asm volatile("s_waitcnt vmcnt(0)"
               : "+v"(a), "+v"(b), "+v"(c), "+v"(d), "+v"(e), "+v"(f) :: "memory");
}

// ---------------------------------------------------------------- k_prep
__global__ void k_prep(const float* __restrict__ wih0, const float* __restrict__ whh0,
                       const float* __restrict__ wih1, const float* __restrict__ whh1,
                       unsigned short* __restrict__ o_wihs, unsigned short* __restrict__ o_wihr,
                       unsigned short* __restrict__ o_whh0,
                       unsigned short* __restrict__ o_wih1, unsigned short* __restrict__ o_whh1,
                       float* __restrict__ h0, float* __restrict__ h1) {
  long idx = (long)blockIdx.x * blockDim.x + threadIdx.x;
  const long ns = 768L * 32, n1 = 768L * 256, nh = 2048L * 256;
  if (idx < ns) { long r = idx >> 5, c = idx & 31;
                  o_wihs[idx] = f2bf(wih0[r * 48 + c]); return; }
  idx -= ns;
  if (idx < ns) { long r = idx >> 5, c = idx & 31;
                  o_wihr[idx] = (c < 16) ? f2bf(wih0[r * 48 + 32 + c]) : (unsigned short)0; return; }
  idx -= ns;
  if (idx < n1) { o_whh0[idx] = f2bf(whh0[idx]); return; }
  idx -= n1;
  if (idx < n1) { o_wih1[idx] = f2bf(wih1[idx]); return; }
  idx -= n1;
  if (idx < n1) { o_whh1[idx] = f2bf(whh1[idx]); return; }
  idx -= n1;
  if (idx < nh) { h0[idx] = 0.f; return; }
  idx -= nh;
  if (idx < nh) { h1[idx] = 0.f; return; }
}

// ---------------------------------------------------------------- k_layer0
// 256 WG x 512 thr, 8 batch rows/WG (MFMA rows 8..15 = finite duplicates).
// Wave wv owns h-cols [32wv,32wv+32): tiles f0..5={r0,r1,z0,z1,n0,n1},
// nt = (f>>1)*16 + 2*wv + (f&1).
__global__ __launch_bounds__(THREADS, 2) void k_layer0(
    const float* __restrict__ obs,
    const unsigned short* __restrict__ g_wihs,  // [768][32] state part
    const unsigned short* __restrict__ g_wihr,  // [768][32] ref part (hi 16 zero)
    const unsigned short* __restrict__ g_whh,   // [768][256]
    const float* __restrict__ b_ih, const float* __restrict__ b_hh,
    float* __restrict__ h0state,                // [2048][256] fp32
    unsigned short* __restrict__ out0c,         // [Tc][2048][256] bf16
    int t0, int Tc) {
  __shared__ __align__(16) unsigned short s_whh6[768 * 40];   // ks=6 strip
  __shared__ __align__(16) unsigned short s_whh7[768 * 40];   // ks=7 strip
  __shared__ __align__(16) unsigned short s_hA[2][16 * 264];  // h bf16 dbuf
  __shared__ __align__(16) unsigned short s_x[2][16 * 32];    // refs (hi 16 zero)
  __shared__ __align__(16) unsigned short s_state[16 * 32];

  const int tid = threadIdx.x;
  const int wv = tid >> 6, lane = tid & 63, ln = lane & 15, qd = lane >> 4;
  const int b0 = blockIdx.x * M;

  for (int i = tid * 8; i < 768 * 32; i += THREADS * 8) {
    int m = i >> 5, c = i & 31;
    *(bfrag8*)&s_whh6[m * 40 + c] = *(const bfrag8*)&g_whh[m * 256 + 192 + c];
    *(bfrag8*)&s_whh7[m * 40 + c] = *(const bfrag8*)&g_whh[m * 256 + 224 + c];
  }
  { int r = tid >> 5, c = tid & 31;  // rows 8..15 duplicate 0..7 (quarantined)
    s_state[tid] = f2bf(obs[(size_t)(b0 + (r & 7)) * OBS_STRIDE + c]); }
  if (tid < 256) {
    int r = tid >> 4, c = tid & 15;
    s_x[0][r * 32 + c] =
        f2bf(obs[(size_t)(b0 + (r & 7)) * OBS_STRIDE + 32 + (size_t)t0 * 16 + c]);
    s_x[0][r * 32 + 16 + c] = 0;
    s_x[1][r * 32 + 16 + c] = 0;
  }

  // forced-resident w_hh ks0..5 (144 regs)
  bfrag8 wf[6][6];
#pragma unroll
  for (int ks = 0; ks < 6; ++ks) {
#pragma unroll
    for (int f = 0; f < 6; ++f) {
      int nt = (f >> 1) * 16 + 2 * wv + (f & 1);
      ld16_async(wf[f][ks], g_whh + (size_t)(nt * 16 + ln) * 256 + ks * 32 + qd * 8);
    }
    wait6(wf[0][ks], wf[1][ks], wf[2][ks], wf[3][ks], wf[4][ks], wf[5][ks]);
  }
  bfrag8 wir[6];
#pragma unroll
  for (int f = 0; f < 6; ++f) {
    int nt = (f >> 1) * 16 + 2 * wv + (f & 1);
    wir[f] = *(const bfrag8*)&g_wihr[(size_t)(nt * 16 + ln) * 32 + qd * 8];
  }
  float bias_hn[2];
#pragma unroll
  for (int p = 0; p < 2; ++p) bias_hn[p] = b_hh[512 + wv * 32 + p * 16 + ln];

  float h[2][4];
#pragma unroll
  for (int p = 0; p < 2; ++p)
#pragma unroll
    for (int i = 0; i < 4; ++i)
      h[p][i] = (qd < 2)
          ? h0state[(size_t)(b0 + qd * 4 + i) * H + wv * 32 + p * 16 + ln] : 0.f;

  __syncthreads();  // s_state / s_x ready

  // time-invariant state-GEMM + bias fold (rows 8..15 quarantined)
  floatx4 cc[6];
  {
    bfrag8 a_st = *(const bfrag8*)&s_state[ln * 32 + qd * 8];
#pragma unroll
    for (int f = 0; f < 6; ++f) {
      int nt = (f >> 1) * 16 + 2 * wv + (f & 1);
      int m = nt * 16 + ln;
      bfrag8 b_st = *(const bfrag8*)&g_wihs[(size_t)m * 32 + qd * 8];
      cc[f] = MFMA16(a_st, b_st, ((floatx4){0.f, 0.f, 0.f, 0.f}));
      float badd = b_ih[m] + ((f < 4) ? b_hh[m] : 0.f);
#pragma unroll
      for (int i = 0; i < 4; ++i) cc[f][i] += badd;
    }
  }
#pragma unroll
  for (int p = 0; p < 2; ++p)
#pragma unroll
    for (int i = 0; i < 4; ++i)
      s_hA[0][(qd * 4 + i) * 264 + wv * 32 + p * 16 + ln] = f2bf(h[p][i]);
  __syncthreads();

  for (int tt = 0; tt < Tc; ++tt) {
    const int cur = tt & 1, nxt = cur ^ 1;
    float nref = 0.f;
    {
      int tl = (tt + 1 < Tc) ? tt + 1 : tt;
      if (tid < 256)
        nref = obs[(size_t)(b0 + ((tid >> 4) & 7)) * OBS_STRIDE + 32 +
                   (size_t)(t0 + tl) * 16 + (tid & 15)];
    }

    floatx4 C[8];  // 0,1=r 2,3=z 4,5=xn 6,7=hn
#pragma unroll
    for (int f = 0; f < 6; ++f) C[f] = cc[f];
    C[6] = (floatx4){0.f, 0.f, 0.f, 0.f};
    C[7] = (floatx4){0.f, 0.f, 0.f, 0.f};

    {  // ref GEMM (K=32, hi half zero)
      bfrag8 ax = *(const bfrag8*)&s_x[cur][ln * 32 + qd * 8];
      C[0] = MFMA16(ax, wir[0], C[0]);
      C[1] = MFMA16(ax, wir[1], C[1]);
      C[2] = MFMA16(ax, wir[2], C[2]);
      C[3] = MFMA16(ax, wir[3], C[3]);
      C[4] = MFMA16(ax, wir[4], C[4]);
      C[5] = MFMA16(ax, wir[5], C[5]);
    }
#pragma unroll
    for (int ks = 0; ks < 6; ++ks) {  // recurrent ks0..5 from registers
      bfrag8 ah = *(const bfrag8*)&s_hA[cur][ln * 264 + ks * 32 + qd * 8];
      C[0] = MFMA16(ah, wf[0][ks], C[0]);
      C[1] = MFMA16(ah, wf[1][ks], C[1]);
      C[2] = MFMA16(ah, wf[2][ks], C[2]);
      C[3] = MFMA16(ah, wf[3][ks], C[3]);
      C[6] = MFMA16(ah, wf[4][ks], C[6]);
      C[7] = MFMA16(ah, wf[5][ks], C[7]);
    }
    {  // ks6 strip
      bfrag8 ah = *(const bfrag8*)&s_hA[cur][ln * 264 + 192 + qd * 8];
#pragma unroll
      for (int f = 0; f < 6; ++f) {
        int nt = (f >> 1) * 16 + 2 * wv + (f & 1);
        bfrag8 bh = *(const bfrag8*)&s_whh6[(nt * 16 + ln) * 40 + qd * 8];
        int ci = (f < 4) ? f : f + 2;
        C[ci] = MFMA16(ah, bh, C[ci]);
      }
    }
    {  // ks7 strip
      bfrag8 ah = *(const bfrag8*)&s_hA[cur][ln * 264 + 224 + qd * 8];
#pragma unroll
      for (int f = 0; f < 6; ++f) {
        int nt = (f >> 1) * 16 + 2 * wv + (f & 1);
        bfrag8 bh = *(const bfrag8*)&s_whh7[(nt * 16 + ln) * 40 + qd * 8];
        int ci = (f < 4) ? f : f + 2;
        C[ci] = MFMA16(ah, bh, C[ci]);
      }
    }
#pragma unroll
    for (int p = 0; p < 2; ++p)
#pragma unroll
      for (int i = 0; i < 4; ++i) {
        float r = fast_sigmoid(C[0 + p][i]);
        float z = fast_sigmoid(C[2 + p][i]);
        float n = fast_tanh(C[4 + p][i] + r * (C[6 + p][i] + bias_hn[p]));
        h[p][i] = n + z * (h[p][i] - n);
      }
#pragma unroll
    for (int p = 0; p < 2; ++p)
#pragma unroll
      for (int i = 0; i < 4; ++i) {
        unsigned short us = f2bf(h[p][i]);
        if (qd < 2)
          out0c[((size_t)tt * 2048 + b0 + qd * 4 + i) * 256 + wv * 32 + p * 16 + ln] = us;
        s_hA[nxt][(qd * 4 + i) * 264 + wv * 32 + p * 16 + ln] = us;
      }
    if (tid < 256) s_x[nxt][(tid >> 4) * 32 + (tid & 15)] = f2bf(nref);
    __syncthreads();
  }
  if (qd < 2) {
#pragma unroll
    for (int p = 0; p < 2; ++p)
#pragma unroll
      for (int i = 0; i < 4; ++i)
        h0state[(size_t)(b0 + qd * 4 + i) * H + wv * 32 + p * 16 + ln] = h[p][i];
  }
}

// ---------------------------------------------------------------- k_xg1
// grid = Tc*16; WG = (tt, 128 batch rows). Wave wv owns gate-tiles 6wv..6wv+5.
// out: xg1c[tt][bblk8(256)][768][8]  (8-row batch blocks, matches k_layer1 WGs)
__global__ __launch_bounds__(THREADS, 2) void k_xg1(
    const unsigned short* __restrict__ out0c,  // [Tc][2048][256]
    const unsigned short* __restrict__ g_wih1, // [768][256]
    unsigned short* __restrict__ xg1c,
    int Tc) {
  const int tid = threadIdx.x;
  const int wv = tid >> 6, lane = tid & 63, ln = lane & 15, qd = lane >> 4;
  const int tt = blockIdx.x >> 4;
  const int b0 = (blockIdx.x & 15) * 128;

  bfrag8 af[6][8];  // forced-resident w_ih_l1 A-fragments (192 regs)
#pragma unroll
  for (int ks = 0; ks < 8; ++ks) {
#pragma unroll
    for (int f = 0; f < 6; ++f) {
      ld16_async(af[f][ks],
                 g_wih1 + (size_t)((wv * 6 + f) * 16 + ln) * 256 + ks * 32 + qd * 8);
    }
    wait6(af[0][ks], af[1][ks], af[2][ks], af[3][ks], af[4][ks], af[5][ks]);
  }
  for (int bt = 0; bt < 8; ++bt) {
    const int bb = b0 + bt * 16;
    floatx4 C[6];
#pragma unroll
    for (int f = 0; f < 6; ++f) C[f] = (floatx4){0.f, 0.f, 0.f, 0.f};
    const unsigned short* brow = out0c + ((size_t)tt * 2048 + bb + ln) * 256 + qd * 8;
#pragma unroll
    for (int ks = 0; ks < 8; ++ks) {
      bfrag8 bfr = *(const bfrag8*)(brow + ks * 32);
#pragma unroll
      for (int f = 0; f < 6; ++f) C[f] = MFMA16(af[f][ks], bfr, C[f]);
    }
    // store: batch row bb+ln -> 8-block (bb>>3)+(ln>>3), sub-row ln&7
    const size_t obase = (((size_t)tt * 256 + (bb >> 3) + (ln >> 3)) * 768) * 8 + (ln & 7);
#pragma unroll
    for (int f = 0; f < 6; ++f) {
      int nt = wv * 6 + f;
#pragma unroll
      for (int i = 0; i < 4; ++i) {
        int m = nt * 16 + qd * 4 + i;
        xg1c[obase + (size_t)m * 8] = f2bf(C[f][i]);
      }
    }
  }
}

// ---------------------------------------------------------------- k_layer1
// 256 WG x 512 thr, 8 batch rows/WG; xg prefetch depth-1 in registers.
__global__ __launch_bounds__(THREADS, 2) void k_layer1(
    const unsigned short* __restrict__ xg1c,   // [Tc][256][768][8]
    const unsigned short* __restrict__ g_whh,  // [768][256]
    const float* __restrict__ b_ih, const float* __restrict__ b_hh,
    float* __restrict__ h1state,
    const float* __restrict__ fc_w, const float* __restrict__ fc_b,
    const float* __restrict__ act_high, const float* __restrict__ act_low,
    float* __restrict__ dout,
    int Tc, int is_last) {
  __shared__ __align__(16) unsigned short s_whh7[768 * 40];
  __shared__ __align__(16) unsigned short s_hA[2][16 * 264];

  const int tid = threadIdx.x;
  const int wv = tid >> 6, lane = tid & 63, ln = lane & 15, qd = lane >> 4;
  const int b0 = blockIdx.x * M;
  const int bblk = blockIdx.x;  // 8-row block index

  for (int i = tid * 8; i < 768 * 32; i += THREADS * 8) {
    int m = i >> 5, c = i & 31;
    *(bfrag8*)&s_whh7[m * 40 + c] = *(const bfrag8*)&g_whh[m * 256 + 224 + c];
  }
  // forced-resident w_hh_l1 ks0..6 (168 regs)
  bfrag8 wf[6][7];
#pragma unroll
  for (int ks = 0; ks < 7; ++ks) {
#pragma unroll
    for (int f = 0; f < 6; ++f) {
      int nt = (f >> 1) * 16 + 2 * wv + (f & 1);
      ld16_async(wf[f][ks], g_whh + (size_t)(nt * 16 + ln) * 256 + ks * 32 + qd * 8);
    }
    wait6(wf[0][ks], wf[1][ks], wf[2][ks], wf[3][ks], wf[4][ks], wf[5][ks]);
  }
  float bias_r[2], bias_z[2], bias_xn[2], bias_hn[2];
#pragma unroll
  for (int p = 0; p < 2; ++p) {
    int col = wv * 32 + p * 16 + ln;
    bias_r[p] = b_ih[col] + b_hh[col];
    bias_z[p] = b_ih[256 + col] + b_hh[256 + col];
    bias_xn[p] = b_ih[512 + col];
    bias_hn[p] = b_hh[512 + col];
  }
  float h[2][4];
#pragma unroll
  for (int p = 0; p < 2; ++p)
#pragma unroll
    for (int i = 0; i < 4; ++i)
      h[p][i] = (qd < 2)
          ? h1state[(size_t)(b0 + qd * 4 + i) * H + wv * 32 + p * 16 + ln] : 0.f;
#pragma unroll
  for (int p = 0; p < 2; ++p)
#pragma unroll
    for (int i = 0; i < 4; ++i)
      s_hA[0][(qd * 4 + i) * 264 + wv * 32 + p * 16 + ln] = f2bf(h[p][i]);

  // xg offsets within one [768][8] block: rows (qd&1)*4..+3 (qd>=2 duplicates)
  size_t offx[2][3];
#pragma unroll
  for (int p = 0; p < 2; ++p) {
    int col = wv * 32 + p * 16 + ln;
#pragma unroll
    for (int g = 0; g < 3; ++g)
      offx[p][g] = (size_t)(g * 256 + col) * 8 + (qd & 1) * 4;
  }
  // prefetch step 0
  bfrag4 xr[2], xz[2], xn[2];
  {
    const unsigned short* xb = xg1c + ((size_t)0 * 256 + bblk) * (768 * 8);
#pragma unroll
    for (int p = 0; p < 2; ++p) {
      xr[p] = *(const bfrag4*)&xb[offx[p][0]];
      xz[p] = *(const bfrag4*)&xb[offx[p][1]];
      xn[p] = *(const bfrag4*)&xb[offx[p][2]];
    }
  }
  __syncthreads();

  for (int tt = 0; tt < Tc; ++tt) {
    const int cur = tt & 1, nxt = cur ^ 1;
    // issue NEXT step's xg loads now; full step of latency slack
    bfrag4 nxr[2], nxz[2], nxn[2];
    {
      int tl = (tt + 1 < Tc) ? tt + 1 : tt;
      const unsigned short* xb = xg1c + ((size_t)tl * 256 + bblk) * (768 * 8);
#pragma unroll
      for (int p = 0; p < 2; ++p) {
        nxr[p] = *(const bfrag4*)&xb[offx[p][0]];
        nxz[p] = *(const bfrag4*)&xb[offx[p][1]];
        nxn[p] = *(const bfrag4*)&xb[offx[p][2]];
      }
    }

    floatx4 C[6];  // 0,1=r 2,3=z 4,5=hn
#pragma unroll
    for (int i = 0; i < 6; ++i) C[i] = (floatx4){0.f, 0.f, 0.f, 0.f};
#pragma unroll
    for (int ks = 0; ks < 7; ++ks) {
      bfrag8 ah = *(const bfrag8*)&s_hA[cur][ln * 264 + ks * 32 + qd * 8];
      C[0] = MFMA16(ah, wf[0][ks], C[0]);
      C[1] = MFMA16(ah, wf[1][ks], C[1]);
      C[2] = MFMA16(ah, wf[2][ks], C[2]);
      C[3] = MFMA16(ah, wf[3][ks], C[3]);
      C[4] = MFMA16(ah, wf[4][ks], C[4]);
      C[5] = MFMA16(ah, wf[5][ks], C[5]);
    }
    {
      bfrag8 ah = *(const bfrag8*)&s_hA[cur][ln * 264 + 224 + qd * 8];
#pragma unroll
      for (int f = 0; f < 6; ++f) {
        int nt = (f >> 1) * 16 + 2 * wv + (f & 1);
        bfrag8 bh = *(const bfrag8*)&s_whh7[(nt * 16 + ln) * 40 + qd * 8];
        C[f] = MFMA16(ah, bh, C[f]);
      }
    }
#pragma unroll
    for (int p = 0; p < 2; ++p)
#pragma unroll
      for (int i = 0; i < 4; ++i) {
        float r = fast_sigmoid(C[0 + p][i] + bf2f((unsigned short)xr[p][i]) + bias_r[p]);
        float z = fast_sigmoid(C[2 + p][i] + bf2f((unsigned short)xz[p][i]) + bias_z[p]);
        float n = fast_tanh(bf2f((unsigned short)xn[p][i]) + bias_xn[p] +
                            r * (C[4 + p][i] + bias_hn[p]));
        h[p][i] = n + z * (h[p][i] - n);
        s_hA[nxt][(qd * 4 + i) * 264 + wv * 32 + p * 16 + ln] = f2bf(h[p][i]);
      }
#pragma unroll
    for (int p = 0; p < 2; ++p) {
      xr[p] = nxr[p]; xz[p] = nxz[p]; xn[p] = nxn[p];
    }
    __syncthreads();
  }
  if (qd < 2) {
#pragma unroll
    for (int p = 0; p < 2; ++p)
#pragma unroll
      for (int i = 0; i < 4; ++i)
        h1state[(size_t)(b0 + qd * 4 + i) * H + wv * 32 + p * 16 + ln] = h[p][i];
  }

  if (is_last) {
    // parallel FC tail: tid = r*32 + a*16 + kseg (rows r<8 real)
    const int fb = Tc & 1;
    int r = tid >> 5, a = (tid >> 4) & 1, kseg = tid & 15;
    float acc = 0.f;
#pragma unroll
    for (int j = 0; j < 16; ++j) {
      int k = kseg * 16 + j;
      acc += bf2f(s_hA[fb][r * 264 + k]) * fc_w[a * H + k];
    }
    acc += __shfl_down(acc, 8);
    acc += __shfl_down(acc, 4);
    acc += __shfl_down(acc, 2);
    acc += __shfl_down(acc, 1);
    if (kseg == 0 && r < 8) {
      acc += fc_b[a];
      float hi = act_high[a], lo = act_low[a];
      float th = fast_tanh(acc);
      dout[(size_t)(b0 + r) * 2 + a] = 0.5f * (hi - lo) * th + 0.5f * (hi + lo);
    }
  }
}

// ---------------------------------------------------------------- host
extern "C" void kernel_launch(void* const* d_in, const int* in_sizes, int n_in,
                              void* d_out, int out_size, void* d_ws, size_t ws_size,
                              hipStream_t stream) {
  const float* obs  = (const float*)d_in[0];
  const float* wih0 = (const float*)d_in[1];
  const float* whh0 = (const float*)d_in[2];
  const float* bih0 = (const float*)d_in[3];
  const float* bhh0 = (const float*)d_in[4];
  const float* wih1 = (const float*)d_in[5];
  const float* whh1 = (const float*)d_in[6];
  const float* bih1 = (const float*)d_in[7];
  const float* bhh1 = (const float*)d_in[8];
  const float* fcw  = (const float*)d_in[9];
  const float* fcb  = (const float*)d_in[10];
  const float* ahigh= (const float*)d_in[11];
  const float* alow = (const float*)d_in[12];

  char* ws = (char*)d_ws;
  unsigned short* ws_wihs = (unsigned short*)(ws + 0);        // 49152
  unsigned short* ws_wihr = (unsigned short*)(ws + 49152);    // 49152
  unsigned short* ws_whh0 = (unsigned short*)(ws + 98304);    // 393216
  unsigned short* ws_wih1 = (unsigned short*)(ws + 491520);   // 393216
  unsigned short* ws_whh1 = (unsigned short*)(ws + 884736);   // 393216
  float* h0 = (float*)(ws + 1277952);                          // 2 MiB
  float* h1 = (float*)(ws + 3375104);                          // 2 MiB
  const size_t base = 5472256;

  int Tc = 1;
  const int cands[7] = {25, 20, 10, 5, 4, 2, 1};
  for (int i = 0; i < 7; ++i) {
    size_t need = base + (size_t)4194304 * cands[i];
    if (need <= ws_size) { Tc = cands[i]; break; }
  }
  unsigned short* out0c = (unsigned short*)(ws + base);
  unsigned short* xg1c  = (unsigned short*)(ws + base + (size_t)1048576 * Tc);

  const long total_prep = 2 * 768L * 32 + 3 * 768L * 256 + 2 * 2048L * 256;
  k_prep<<<(int)((total_prep + 255) / 256), 256, 0, stream>>>(
      wih0, whh0, wih1, whh1, ws_wihs, ws_wihr, ws_whh0, ws_wih1, ws_whh1, h0, h1);

  for (int t0 = 0; t0 < 100; t0 += Tc) {
    k_layer0<<<256, THREADS, 0, stream>>>(obs, ws_wihs, ws_wihr, ws_whh0, bih0, bhh0,
                                          h0, out0c, t0, Tc);
    k_xg1<<<Tc * 16, THREADS, 0, stream>>>(out0c, ws_wih1, xg1c, Tc);
    k_layer1<<<256, THREADS, 0, stream>>>(xg1c, ws_whh1, bih1, bhh1, h1,
                                          fcw, fcb, ahigh, alow, (float*)d_out,
                                          Tc, (t0 + Tc >= 100) ? 1 : 0);
  }
}

// Round 6
// 650.914 us; speedup vs baseline: 1.6599x; 1.6599x over previous
//
#include <hip/hip_runtime.h>
#include <hip/hip_bf16.h>
#include <stdint.h>
#include <stddef.h>

// GRU policy: B=2048, T=100, H=256, IN=48 (32 state + 16 ref), ACT=2.
// R6: back to M=16/128-WG per role (R4/R5's M=8 was a thinking error: time =
//     Tc x per-WG chain latency; grid size doesn't shorten the chain).
//     NEW: (1) fused pipeline kernel: blocks 0..127 = layer0 chunk c,
//     blocks 128..255 = layer1 chunk c-1 (independent -> overlap, no sync);
//     (2) gates via raw v_rcp/v_exp2 (no IEEE div sequences, no clamps);
//     (3) coalesced out0c store (b128 from s_hA) off the barrier-drain path;
//     (4) k_xg1 = proven R3 version.

#define OBS_STRIDE 1632
#define H 256
#define M 16
#define THREADS 512

typedef __attribute__((ext_vector_type(8))) short bfrag8;   // 8 bf16 (4 VGPR)
typedef __attribute__((ext_vector_type(4))) short bfrag4;   // 4 bf16 (8B)
typedef __attribute__((ext_vector_type(4))) float floatx4;  // MFMA C/D

#define MFMA16(a, b, c) __builtin_amdgcn_mfma_f32_16x16x32_bf16((a), (b), (c), 0, 0, 0)

__device__ __forceinline__ unsigned short f2bf(float f) {
  union { float f; unsigned int i; } v; v.f = f;
  unsigned int i = v.i + 0x7FFFu + ((v.i >> 16) & 1u);  // RNE
  return (unsigned short)(i >> 16);
}
__device__ __forceinline__ float bf2f(unsigned short u) {
  union { unsigned int i; float f; } v; v.i = ((unsigned int)u) << 16; return v.f;
}
// sigmoid(x) = rcp(1 + 2^(-x*log2e));  saturates correctly at +-inf, no clamps.
__device__ __forceinline__ float fsigm(float x) {
  return __builtin_amdgcn_rcpf(1.f + __builtin_amdgcn_exp2f(-1.44269504f * x));
}
// tanh(x) = 1 - 2*rcp(1 + 2^(x*2log2e));  saturates correctly, no clamps.
__device__ __forceinline__ float ftanh(float x) {
  return 1.f - 2.f * __builtin_amdgcn_rcpf(1.f + __builtin_amdgcn_exp2f(2.88539008f * x));
}

// Forced (non-rematerializable) 16B global load -> stays in VGPR/AGPR file.
__device__ __forceinline__ void ld16_async(bfrag8& d, const unsigned short* p) {
  asm volatile("global_load_dwordx4 %0, %1, off" : "=v"(d) : "v"(p));
}
__device__ __forceinline__ void wait6(bfrag8& a, bfrag8& b, bfrag8& c,
                                      bfrag8& d, bfrag8& e, bfrag8& f) {
  asm volatile("s_waitcnt vmcnt(0)"
               : "+v"(a), "+v"(b), "+v"(c), "+v"(d), "+v"(e), "+v"(f) :: "memory");
}

// ---------------------------------------------------------------- k_prep
__global__ void k_prep(const float* __restrict__ wih0, const float* __restrict__ whh0,
                       const float* __restrict__ wih1, const float* __restrict__ whh1,
                       unsigned short* __restrict__ o_wihs, unsigned short* __restrict__ o_wihr,
                       unsigned short* __restrict__ o_whh0,
                       unsigned short* __restrict__ o_wih1, unsigned short* __restrict__ o_whh1,
                       float* __restrict__ h0, float* __restrict__ h1) {
  long idx = (long)blockIdx.x * blockDim.x + threadIdx.x;
  const long ns = 768L * 32, n1 = 768L * 256, nh = 2048L * 256;
  if (idx < ns) { long r = idx >> 5, c = idx & 31;
                  o_wihs[idx] = f2bf(wih0[r * 48 + c]); return; }
  idx -= ns;
  if (idx < ns) { long r = idx >> 5, c = idx & 31;
                  o_wihr[idx] = (c < 16) ? f2bf(wih0[r * 48 + 32 + c]) : (unsigned short)0; return; }
  idx -= ns;
  if (idx < n1) { o_whh0[idx] = f2bf(whh0[idx]); return; }
  idx -= n1;
  if (idx < n1) { o_wih1[idx] = f2bf(wih1[idx]); return; }
  idx -= n1;
  if (idx < n1) { o_whh1[idx] = f2bf(whh1[idx]); return; }
  idx -= n1;
  if (idx < nh) { h0[idx] = 0.f; return; }
  idx -= nh;
  if (idx < nh) { h1[idx] = 0.f; return; }
}

// ---------------------------------------------------------------- k_fused
// 256 WGs: blocks 0..127 run layer0 on chunk c (t0..t0+Tc), blocks 128..255
// run layer1 on chunk c-1 (xg1c buffer). Roles are fully independent.
// Per role: 16 batch rows/WG. Wave wv owns h-cols [32wv,32wv+32):
// tiles f0..5={r0,r1,z0,z1,n0,n1}, nt=(f>>1)*16+2*wv+(f&1).
__global__ __launch_bounds__(THREADS, 2) void k_fused(
    const float* __restrict__ obs,
    const unsigned short* __restrict__ g_wihs,  // [768][32]
    const unsigned short* __restrict__ g_wihr,  // [768][32] (hi 16 zero)
    const unsigned short* __restrict__ g_whh0,  // [768][256]
    const float* __restrict__ b_ih0, const float* __restrict__ b_hh0,
    float* __restrict__ h0state,
    unsigned short* __restrict__ out0c,         // [Tc][2048][256]
    const unsigned short* __restrict__ xg1c,    // [Tc][128][768][16]
    const unsigned short* __restrict__ g_whh1,  // [768][256]
    const float* __restrict__ b_ih1, const float* __restrict__ b_hh1,
    float* __restrict__ h1state,
    const float* __restrict__ fc_w, const float* __restrict__ fc_b,
    const float* __restrict__ act_high, const float* __restrict__ act_low,
    float* __restrict__ dout,
    int t0, int Tc, int do_l0, int do_l1, int is_last) {
  // LDS union: layer0 needs 143,872 B; layer1 needs 78,336 B.
  __shared__ __align__(16) unsigned short s_mem[71936];

  const int tid = threadIdx.x;
  const int wv = tid >> 6, lane = tid & 63, ln = lane & 15, qd = lane >> 4;
  const int role = blockIdx.x >> 7;          // 0 = layer0, 1 = layer1
  const int bblk = blockIdx.x & 127;
  const int b0 = bblk * M;

  if (role == 0) {
    // ======================= LAYER 0 =======================
    if (!do_l0) return;
    unsigned short* s_whh6 = s_mem;           // [768*40]
    unsigned short* s_whh7 = s_mem + 30720;   // [768*40]
    unsigned short* s_hA   = s_mem + 61440;   // [2][16*264]
    unsigned short* s_x    = s_mem + 69888;   // [2][16*32]
    unsigned short* s_st   = s_mem + 70912;   // [16*32]

    for (int i = tid * 8; i < 768 * 32; i += THREADS * 8) {
      int m = i >> 5, c = i & 31;
      *(bfrag8*)&s_whh6[m * 40 + c] = *(const bfrag8*)&g_whh0[m * 256 + 192 + c];
      *(bfrag8*)&s_whh7[m * 40 + c] = *(const bfrag8*)&g_whh0[m * 256 + 224 + c];
    }
    { int r = tid >> 5, c = tid & 31;
      s_st[tid] = f2bf(obs[(size_t)(b0 + r) * OBS_STRIDE + c]); }
    if (tid < 256) {
      int r = tid >> 4, c = tid & 15;
      s_x[r * 32 + c] = f2bf(obs[(size_t)(b0 + r) * OBS_STRIDE + 32 + (size_t)t0 * 16 + c]);
      s_x[r * 32 + 16 + c] = 0;
      s_x[512 + r * 32 + 16 + c] = 0;
    }

    bfrag8 wf[6][6];  // forced-resident w_hh0 ks0..5
#pragma unroll
    for (int ks = 0; ks < 6; ++ks) {
#pragma unroll
      for (int f = 0; f < 6; ++f) {
        int nt = (f >> 1) * 16 + 2 * wv + (f & 1);
        ld16_async(wf[f][ks], g_whh0 + (size_t)(nt * 16 + ln) * 256 + ks * 32 + qd * 8);
      }
      wait6(wf[0][ks], wf[1][ks], wf[2][ks], wf[3][ks], wf[4][ks], wf[5][ks]);
    }
    bfrag8 wir[6];
#pragma unroll
    for (int f = 0; f < 6; ++f) {
      int nt = (f >> 1) * 16 + 2 * wv + (f & 1);
      wir[f] = *(const bfrag8*)&g_wihr[(size_t)(nt * 16 + ln) * 32 + qd * 8];
    }
    float bias_hn[2];
#pragma unroll
    for (int p = 0; p < 2; ++p) bias_hn[p] = b_hh0[512 + wv * 32 + p * 16 + ln];

    float h[2][4];
#pragma unroll
    for (int p = 0; p < 2; ++p)
#pragma unroll
      for (int i = 0; i < 4; ++i)
        h[p][i] = h0state[(size_t)(b0 + qd * 4 + i) * H + wv * 32 + p * 16 + ln];

    __syncthreads();

    // time-invariant state GEMM + bias fold
    floatx4 cc[6];
    {
      bfrag8 a_st = *(const bfrag8*)&s_st[ln * 32 + qd * 8];
#pragma unroll
      for (int f = 0; f < 6; ++f) {
        int nt = (f >> 1) * 16 + 2 * wv + (f & 1);
        int m = nt * 16 + ln;
        bfrag8 b_st = *(const bfrag8*)&g_wihs[(size_t)m * 32 + qd * 8];
        cc[f] = MFMA16(a_st, b_st, ((floatx4){0.f, 0.f, 0.f, 0.f}));
        float badd = b_ih0[m] + ((f < 4) ? b_hh0[m] : 0.f);
#pragma unroll
        for (int i = 0; i < 4; ++i) cc[f][i] += badd;
      }
    }
#pragma unroll
    for (int p = 0; p < 2; ++p)
#pragma unroll
      for (int i = 0; i < 4; ++i)
        s_hA[(qd * 4 + i) * 264 + wv * 32 + p * 16 + ln] = f2bf(h[p][i]);
    __syncthreads();

    const int orow = tid >> 5, ocol = (tid & 31) * 8;
    for (int tt = 0; tt < Tc; ++tt) {
      const int cur = tt & 1, nxt = cur ^ 1;
      // coalesced out0 store of PREVIOUS step's h from s_hA[cur] (stable now)
      if (tt > 0) {
        bfrag8 hv = *(const bfrag8*)&s_hA[cur * 4224 + orow * 264 + ocol];
        *(bfrag8*)&out0c[((size_t)(tt - 1) * 2048 + b0 + orow) * 256 + ocol] = hv;
      }
      float nref = 0.f;
      {
        int tl = (tt + 1 < Tc) ? tt + 1 : tt;
        if (tid < 256)
          nref = obs[(size_t)(b0 + (tid >> 4)) * OBS_STRIDE + 32 +
                     (size_t)(t0 + tl) * 16 + (tid & 15)];
      }

      floatx4 C[8];  // 0,1=r 2,3=z 4,5=xn 6,7=hn
#pragma unroll
      for (int f = 0; f < 6; ++f) C[f] = cc[f];
      C[6] = (floatx4){0.f, 0.f, 0.f, 0.f};
      C[7] = (floatx4){0.f, 0.f, 0.f, 0.f};

      {  // ref GEMM (K=32, hi half zero)
        bfrag8 ax = *(const bfrag8*)&s_x[cur * 512 + ln * 32 + qd * 8];
        C[0] = MFMA16(ax, wir[0], C[0]);
        C[1] = MFMA16(ax, wir[1], C[1]);
        C[2] = MFMA16(ax, wir[2], C[2]);
        C[3] = MFMA16(ax, wir[3], C[3]);
        C[4] = MFMA16(ax, wir[4], C[4]);
        C[5] = MFMA16(ax, wir[5], C[5]);
      }
#pragma unroll
      for (int ks = 0; ks < 6; ++ks) {
        bfrag8 ah = *(const bfrag8*)&s_hA[cur * 4224 + ln * 264 + ks * 32 + qd * 8];
        C[0] = MFMA16(ah, wf[0][ks], C[0]);
        C[1] = MFMA16(ah, wf[1][ks], C[1]);
        C[2] = MFMA16(ah, wf[2][ks], C[2]);
        C[3] = MFMA16(ah, wf[3][ks], C[3]);
        C[6] = MFMA16(ah, wf[4][ks], C[6]);
        C[7] = MFMA16(ah, wf[5][ks], C[7]);
      }
      {  // ks6 strip
        bfrag8 ah = *(const bfrag8*)&s_hA[cur * 4224 + ln * 264 + 192 + qd * 8];
#pragma unroll
        for (int f = 0; f < 6; ++f) {
          int nt = (f >> 1) * 16 + 2 * wv + (f & 1);
          bfrag8 bh = *(const bfrag8*)&s_whh6[(nt * 16 + ln) * 40 + qd * 8];
          int ci = (f < 4) ? f : f + 2;
          C[ci] = MFMA16(ah, bh, C[ci]);
        }
      }
      {  // ks7 strip
        bfrag8 ah = *(const bfrag8*)&s_hA[cur * 4224 + ln * 264 + 224 + qd * 8];
#pragma unroll
        for (int f = 0; f < 6; ++f) {
          int nt = (f >> 1) * 16 + 2 * wv + (f & 1);
          bfrag8 bh = *(const bfrag8*)&s_whh7[(nt * 16 + ln) * 40 + qd * 8];
          int ci = (f < 4) ? f : f + 2;
          C[ci] = MFMA16(ah, bh, C[ci]);
        }
      }
#pragma unroll
      for (int p = 0; p < 2; ++p)
#pragma unroll
        for (int i = 0; i < 4; ++i) {
          float r = fsigm(C[0 + p][i]);
          float z = fsigm(C[2 + p][i]);
          float n = ftanh(C[4 + p][i] + r * (C[6 + p][i] + bias_hn[p]));
          h[p][i] = n + z * (h[p][i] - n);
          s_hA[nxt * 4224 + (qd * 4 + i) * 264 + wv * 32 + p * 16 + ln] = f2bf(h[p][i]);
        }
      if (tid < 256) s_x[nxt * 512 + (tid >> 4) * 32 + (tid & 15)] = f2bf(nref);
      __syncthreads();
    }
    // final out0 store + h0 carry
    {
      const int fb = Tc & 1;
      bfrag8 hv = *(const bfrag8*)&s_hA[fb * 4224 + orow * 264 + ocol];
      *(bfrag8*)&out0c[((size_t)(Tc - 1) * 2048 + b0 + orow) * 256 + ocol] = hv;
    }
#pragma unroll
    for (int p = 0; p < 2; ++p)
#pragma unroll
      for (int i = 0; i < 4; ++i)
        h0state[(size_t)(b0 + qd * 4 + i) * H + wv * 32 + p * 16 + ln] = h[p][i];

  } else {
    // ======================= LAYER 1 =======================
    if (!do_l1) return;
    unsigned short* s_whh7 = s_mem;           // [768*40]
    unsigned short* s_hA   = s_mem + 30720;   // [2][16*264]

    for (int i = tid * 8; i < 768 * 32; i += THREADS * 8) {
      int m = i >> 5, c = i & 31;
      *(bfrag8*)&s_whh7[m * 40 + c] = *(const bfrag8*)&g_whh1[m * 256 + 224 + c];
    }
    bfrag8 wf[6][7];  // forced-resident w_hh1 ks0..6
#pragma unroll
    for (int ks = 0; ks < 7; ++ks) {
#pragma unroll
      for (int f = 0; f < 6; ++f) {
        int nt = (f >> 1) * 16 + 2 * wv + (f & 1);
        ld16_async(wf[f][ks], g_whh1 + (size_t)(nt * 16 + ln) * 256 + ks * 32 + qd * 8);
      }
      wait6(wf[0][ks], wf[1][ks], wf[2][ks], wf[3][ks], wf[4][ks], wf[5][ks]);
    }
    float bias_r[2], bias_z[2], bias_xn[2], bias_hn[2];
#pragma unroll
    for (int p = 0; p < 2; ++p) {
      int col = wv * 32 + p * 16 + ln;
      bias_r[p] = b_ih1[col] + b_hh1[col];
      bias_z[p] = b_ih1[256 + col] + b_hh1[256 + col];
      bias_xn[p] = b_ih1[512 + col];
      bias_hn[p] = b_hh1[512 + col];
    }
    float h[2][4];
#pragma unroll
    for (int p = 0; p < 2; ++p)
#pragma unroll
      for (int i = 0; i < 4; ++i)
        h[p][i] = h1state[(size_t)(b0 + qd * 4 + i) * H + wv * 32 + p * 16 + ln];
#pragma unroll
    for (int p = 0; p < 2; ++p)
#pragma unroll
      for (int i = 0; i < 4; ++i)
        s_hA[(qd * 4 + i) * 264 + wv * 32 + p * 16 + ln] = f2bf(h[p][i]);

    size_t offx[2][3];
#pragma unroll
    for (int p = 0; p < 2; ++p) {
      int col = wv * 32 + p * 16 + ln;
#pragma unroll
      for (int g = 0; g < 3; ++g)
        offx[p][g] = (size_t)(g * 256 + col) * 16 + qd * 4;
    }
    bfrag4 xr[2], xz[2], xn[2];
    {
      const unsigned short* xb = xg1c + (size_t)bblk * (768 * 16);
#pragma unroll
      for (int p = 0; p < 2; ++p) {
        xr[p] = *(const bfrag4*)&xb[offx[p][0]];
        xz[p] = *(const bfrag4*)&xb[offx[p][1]];
        xn[p] = *(const bfrag4*)&xb[offx[p][2]];
      }
    }
    __syncthreads();

    for (int tt = 0; tt < Tc; ++tt) {
      const int cur = tt & 1, nxt = cur ^ 1;
      bfrag4 nxr[2], nxz[2], nxn[2];
      {
        int tl = (tt + 1 < Tc) ? tt + 1 : tt;
        const unsigned short* xb = xg1c + ((size_t)tl * 128 + bblk) * (768 * 16);
#pragma unroll
        for (int p = 0; p < 2; ++p) {
          nxr[p] = *(const bfrag4*)&xb[offx[p][0]];
          nxz[p] = *(const bfrag4*)&xb[offx[p][1]];
          nxn[p] = *(const bfrag4*)&xb[offx[p][2]];
        }
      }

      floatx4 C[6];  // 0,1=r 2,3=z 4,5=hn
#pragma unroll
      for (int i = 0; i < 6; ++i) C[i] = (floatx4){0.f, 0.f, 0.f, 0.f};
#pragma unroll
      for (int ks = 0; ks < 7; ++ks) {
        bfrag8 ah = *(const bfrag8*)&s_hA[cur * 4224 + ln * 264 + ks * 32 + qd * 8];
        C[0] = MFMA16(ah, wf[0][ks], C[0]);
        C[1] = MFMA16(ah, wf[1][ks], C[1]);
        C[2] = MFMA16(ah, wf[2][ks], C[2]);
        C[3] = MFMA16(ah, wf[3][ks], C[3]);
        C[4] = MFMA16(ah, wf[4][ks], C[4]);
        C[5] = MFMA16(ah, wf[5][ks], C[5]);
      }
      {
        bfrag8 ah = *(const bfrag8*)&s_hA[cur * 4224 + ln * 264 + 224 + qd * 8];
#pragma unroll
        for (int f = 0; f < 6; ++f) {
          int nt = (f >> 1) * 16 + 2 * wv + (f & 1);
          bfrag8 bh = *(const bfrag8*)&s_whh7[(nt * 16 + ln) * 40 + qd * 8];
          C[f] = MFMA16(ah, bh, C[f]);
        }
      }
#pragma unroll
      for (int p = 0; p < 2; ++p)
#pragma unroll
        for (int i = 0; i < 4; ++i) {
          float r = fsigm(C[0 + p][i] + bf2f((unsigned short)xr[p][i]) + bias_r[p]);
          float z = fsigm(C[2 + p][i] + bf2f((unsigned short)xz[p][i]) + bias_z[p]);
          float n = ftanh(bf2f((unsigned short)xn[p][i]) + bias_xn[p] +
                          r * (C[4 + p][i] + bias_hn[p]));
          h[p][i] = n + z * (h[p][i] - n);
          s_hA[nxt * 4224 + (qd * 4 + i) * 264 + wv * 32 + p * 16 + ln] = f2bf(h[p][i]);
        }
#pragma unroll
      for (int p = 0; p < 2; ++p) { xr[p] = nxr[p]; xz[p] = nxz[p]; xn[p] = nxn[p]; }
      __syncthreads();
    }
#pragma unroll
    for (int p = 0; p < 2; ++p)
#pragma unroll
      for (int i = 0; i < 4; ++i)
        h1state[(size_t)(b0 + qd * 4 + i) * H + wv * 32 + p * 16 + ln] = h[p][i];

    if (is_last) {
      // parallel FC tail: tid = r*32 + a*16 + kseg
      const int fb = Tc & 1;
      int r = tid >> 5, a = (tid >> 4) & 1, kseg = tid & 15;
      float acc = 0.f;
#pragma unroll
      for (int j = 0; j < 16; ++j) {
        int k = kseg * 16 + j;
        acc += bf2f(s_hA[fb * 4224 + r * 264 + k]) * fc_w[a * H + k];
      }
      acc += __shfl_down(acc, 8);
      acc += __shfl_down(acc, 4);
      acc += __shfl_down(acc, 2);
      acc += __shfl_down(acc, 1);
      if (kseg == 0) {
        acc += fc_b[a];
        float hi = act_high[a], lo = act_low[a];
        float th = ftanh(acc);
        dout[(size_t)(b0 + r) * 2 + a] = 0.5f * (hi - lo) * th + 0.5f * (hi + lo);
      }
    }
  }
}

// ---------------------------------------------------------------- k_xg1
// (R3-proven) grid = Tc*8; WG = (tt, 256 batch). Wave wv owns tiles 6wv..6wv+5.
// out: xg1c[tt][bblk(128)][768][16]
__global__ __launch_bounds__(THREADS, 2) void k_xg1(
    const unsigned short* __restrict__ out0c,  // [Tc][2048][256]
    const unsigned short* __restrict__ g_wih1, // [768][256]
    unsigned short* __restrict__ xg1c,
    int Tc) {
  const int tid = threadIdx.x;
  const int wv = tid >> 6, lane = tid & 63, ln = lane & 15, qd = lane >> 4;
  const int tt = blockIdx.x >> 3;
  const int b0 = (blockIdx.x & 7) * 256;

  bfrag8 af[6][8];  // forced-resident w_ih_l1 A-fragments
#pragma unroll
  for (int ks = 0; ks < 8; ++ks) {
#pragma unroll
    for (int f = 0; f < 6; ++f) {
      ld16_async(af[f][ks],
                 g_wih1 + (size_t)((wv * 6 + f) * 16 + ln) * 256 + ks * 32 + qd * 8);
    }
    wait6(af[0][ks], af[1][ks], af[2][ks], af[3][ks], af[4][ks], af[5][ks]);
  }
  for (int bt = 0; bt < 16; ++bt) {
    const int bb = b0 + bt * 16;
    floatx4 C[6];
#pragma unroll
    for (int f = 0; f < 6; ++f) C[f] = (floatx4){0.f, 0.f, 0.f, 0.f};
    const unsigned short* brow = out0c + ((size_t)tt * 2048 + bb + ln) * 256 + qd * 8;
#pragma unroll
    for (int ks = 0; ks < 8; ++ks) {
      bfrag8 bfr = *(const bfrag8*)(brow + ks * 32);
#pragma unroll
      for (int f = 0; f < 6; ++f) C[f] = MFMA16(af[f][ks], bfr, C[f]);
    }
    const size_t obase = ((size_t)tt * 128 + (bb >> 4)) * (768 * 16);
#pragma unroll
    for (int f = 0; f < 6; ++f) {
      int nt = wv * 6 + f;
#pragma unroll
      for (int i = 0; i < 4; ++i) {
        int m = nt * 16 + qd * 4 + i;
        xg1c[obase + (size_t)m * 16 + ln] = f2bf(C[f][i]);
      }
    }
  }
}

// ---------------------------------------------------------------- host
extern "C" void kernel_launch(void* const* d_in, const int* in_sizes, int n_in,
                              void* d_out, int out_size, void* d_ws, size_t ws_size,
                              hipStream_t stream) {
  const float* obs  = (const float*)d_in[0];
  const float* wih0 = (const float*)d_in[1];
  const float* whh0 = (const float*)d_in[2];
  const float* bih0 = (const float*)d_in[3];
  const float* bhh0 = (const float*)d_in[4];
  const float* wih1 = (const float*)d_in[5];
  const float* whh1 = (const float*)d_in[6];
  const float* bih1 = (const float*)d_in[7];
  const float* bhh1 = (const float*)d_in[8];
  const float* fcw  = (const float*)d_in[9];
  const float* fcb  = (const float*)d_in[10];
  const float* ahigh= (const float*)d_in[11];
  const float* alow = (const float*)d_in[12];

  char* ws = (char*)d_ws;
  unsigned short* ws_wihs = (unsigned short*)(ws + 0);        // 49152
  unsigned short* ws_wihr = (unsigned short*)(ws + 49152);    // 49152
  unsigned short* ws_whh0 = (unsigned short*)(ws + 98304);    // 393216
  unsigned short* ws_wih1 = (unsigned short*)(ws + 491520);   // 393216
  unsigned short* ws_whh1 = (unsigned short*)(ws + 884736);   // 393216
  float* h0 = (float*)(ws + 1277952);                          // 2 MiB
  float* h1 = (float*)(ws + 3375104);                          // 2 MiB
  const size_t base = 5472256;

  int Tc = 1;
  const int cands[7] = {25, 20, 10, 5, 4, 2, 1};
  for (int i = 0; i < 7; ++i) {
    size_t need = base + (size_t)4194304 * cands[i];
    if (need <= ws_size) { Tc = cands[i]; break; }
  }
  unsigned short* out0c = (unsigned short*)(ws + base);
  unsigned short* xg1c  = (unsigned short*)(ws + base + (size_t)1048576 * Tc);
  const int nc = 100 / Tc;

  const long total_prep = 2 * 768L * 32 + 3 * 768L * 256 + 2 * 2048L * 256;
  k_prep<<<(int)((total_prep + 255) / 256), 256, 0, stream>>>(
      wih0, whh0, wih1, whh1, ws_wihs, ws_wihr, ws_whh0, ws_wih1, ws_whh1, h0, h1);

  // 2-stage software pipeline: fused(c) = layer0(c) || layer1(c-1);
  // xg1(c) between fused launches satisfies both data deps via stream order.
  for (int c = 0; c <= nc; ++c) {
    k_fused<<<256, THREADS, 0, stream>>>(
        obs, ws_wihs, ws_wihr, ws_whh0, bih0, bhh0, h0, out0c,
        xg1c, ws_whh1, bih1, bhh1, h1, fcw, fcb, ahigh, alow, (float*)d_out,
        c * Tc, Tc, (c < nc) ? 1 : 0, (c > 0) ? 1 : 0, (c == nc) ? 1 : 0);
    if (c < nc)
      k_xg1<<<Tc * 8, THREADS, 0, stream>>>(out0c, ws_wih1, xg1c, Tc);
  }
}